// Round 14
// baseline (476.284 us; speedup 1.0000x reference)
//
#include <hip/hip_runtime.h>
#include <math.h>

#define B_ 4
#define L_ 4096
#define D_ 512
#define P_ 128
#define V_ 8
#define N_ (B_*L_)
#define NC 64
#define CL (L_/NC)
#define LD ((size_t)L_*D_)
#define PI_F 3.14159265358979323846f

typedef unsigned short ushort;
typedef __attribute__((ext_vector_type(8))) short bh8;
typedef __attribute__((ext_vector_type(4))) float f4;
typedef const __attribute__((address_space(1))) unsigned int gu32;
typedef __attribute__((address_space(3))) unsigned int lu32;

__device__ __forceinline__ float geluf(float v){
    return 0.5f*v*(1.0f+erff(v*0.7071067811865475f));
}
__device__ __forceinline__ float tanhf_fast(float x){
    return 1.0f - 2.0f/(__expf(2.0f*x)+1.0f);
}
__device__ __forceinline__ ushort f2b(float f){
    union { float f; unsigned u; } v; v.f = f;
    unsigned r = (v.u + 0x7fffu + ((v.u >> 16) & 1u)) >> 16;
    return (ushort)r;
}
__device__ __forceinline__ float b2f(ushort h){
    union { unsigned u; float f; } v; v.u = ((unsigned)h) << 16;
    return v.f;
}
__device__ __forceinline__ void gload16(const ushort* g, ushort* l){
    __builtin_amdgcn_global_load_lds((gu32*)g, (lu32*)l, 16, 0, 0);
}
__device__ __forceinline__ int xcd_swz(int orig, int nwg){
    int q8 = nwg >> 3, r8 = nwg & 7;
    int xcd = orig & 7, sub = orig >> 3;
    return (xcd < r8 ? xcd*(q8+1) : r8*(q8+1) + (xcd-r8)*q8) + sub;
}

// ===== dgemm: 128x128, BK=64, XOR swizzle, counted vmcnt(8), 2 blocks/CU
template<int ACT>
__global__ __launch_bounds__(256, 2)
void dgemm_k(const ushort* __restrict__ A, int lda,
             const ushort* __restrict__ Wt, const float* __restrict__ bias,
             ushort* __restrict__ Ob, float* __restrict__ Of,
             int ldc, int K, const float* __restrict__ addbuf)
{
    __shared__ ushort lA[2][128*64];
    __shared__ ushort lB[2][128*64];
    const int tid = threadIdx.x, lane = tid & 63, w = tid >> 6;
    const int wr = w >> 1, wc = w & 1;
    const int nbx = gridDim.x;
    const int wg = xcd_swz(blockIdx.y*nbx + blockIdx.x, nbx*gridDim.y);
    const int row0 = (wg / nbx) * 128, col0 = (wg % nbx) * 128;

    f4 zero4 = {0.f,0.f,0.f,0.f};
    f4 acc[4][4];
    #pragma unroll
    for (int i=0;i<4;i++)
        #pragma unroll
        for (int j=0;j<4;j++) acc[i][j] = zero4;

    auto stage = [&](int buf, int kt){
        #pragma unroll
        for (int is=0; is<4; ++is){
            int id = tid + is*256;
            int r = id >> 3, p = id & 7;
            int srcc = (p ^ (r & 7)) * 8;
            gload16(A + (size_t)(row0 + r)*lda + kt + srcc, &lA[buf][r*64 + p*8]);
        }
        #pragma unroll
        for (int is=0; is<4; ++is){
            int id = tid + is*256;
            int r = id >> 3, p = id & 7;
            int srcc = (p ^ (r & 7)) * 8;
            gload16(Wt + (size_t)(col0 + r)*K + kt + srcc, &lB[buf][r*64 + p*8]);
        }
    };

    const int NT = K >> 6;
    stage(0, 0);
    for (int t2 = 0; t2 < NT; ++t2){
        int cur = t2 & 1;
        if (t2 + 1 < NT){
            stage(cur ^ 1, (t2+1) << 6);
            asm volatile("s_waitcnt vmcnt(8)" ::: "memory");
        } else {
            asm volatile("s_waitcnt vmcnt(0)" ::: "memory");
        }
        __builtin_amdgcn_s_barrier();
        __builtin_amdgcn_sched_barrier(0);
        #pragma unroll
        for (int h=0; h<2; ++h){
            bh8 af[4], bf_[4];
            #pragma unroll
            for (int i=0;i<4;i++){
                int row = wr*64 + i*16 + (lane & 15);
                int pc = (h*4 + (lane >> 4)) ^ (row & 7);
                af[i] = *(const bh8*)&lA[cur][row*64 + pc*8];
            }
            #pragma unroll
            for (int j=0;j<4;j++){
                int row = wc*64 + j*16 + (lane & 15);
                int pc = (h*4 + (lane >> 4)) ^ (row & 7);
                bf_[j] = *(const bh8*)&lB[cur][row*64 + pc*8];
            }
            #pragma unroll
            for (int i=0;i<4;i++)
                #pragma unroll
                for (int j=0;j<4;j++)
                    acc[i][j] = __builtin_amdgcn_mfma_f32_16x16x32_bf16(af[i], bf_[j], acc[i][j], 0, 0, 0);
        }
        __builtin_amdgcn_sched_barrier(0);
        __builtin_amdgcn_s_barrier();
    }

    #pragma unroll
    for (int i=0;i<4;i++){
        int rr = row0 + wr*64 + i*16 + ((lane >> 4) << 2);
        #pragma unroll
        for (int j=0;j<4;j++){
            int cc = col0 + wc*64 + j*16 + (lane & 15);
            float bv = bias[cc];
            #pragma unroll
            for (int q=0;q<4;q++){
                int r = rr + q;
                float t = acc[i][j][q] + bv;
                if (ACT==2){
                    if (addbuf) t += addbuf[(size_t)r*512 + cc];
                    Of[(size_t)r*ldc + cc] = t;
                } else {
                    if (ACT==1) t = geluf(t);
                    Ob[(size_t)r*ldc + cc] = f2b(t);
                }
            }
        }
    }
}

// ===== egemm: 256x256, 8 waves, wave-tile 128x64, BK=64 (o1 only; proven r11/12)
template<int ACT>
__global__ __launch_bounds__(512, 1)
void egemm_k(const ushort* __restrict__ A, int lda,
             const ushort* __restrict__ Wt, const float* __restrict__ bias,
             ushort* __restrict__ Ob, float* __restrict__ Of,
             int ldc, int K, const float* __restrict__ addbuf)
{
    __shared__ ushort lA[2][256*64];
    __shared__ ushort lB[2][256*64];
    const int tid = threadIdx.x, lane = tid & 63, w = tid >> 6;
    const int wr = w >> 2, wc = w & 3;
    const int nbx = gridDim.x;
    const int wg = xcd_swz(blockIdx.y*nbx + blockIdx.x, nbx*gridDim.y);
    const int row0 = (wg / nbx) * 256, col0 = (wg % nbx) * 256;

    f4 zero4 = {0.f,0.f,0.f,0.f};
    f4 acc[8][4];
    #pragma unroll
    for (int i=0;i<8;i++)
        #pragma unroll
        for (int j=0;j<4;j++) acc[i][j] = zero4;

    auto stage = [&](int buf, int kt){
        #pragma unroll
        for (int is=0; is<4; ++is){
            int id = tid + is*512;
            int r = id >> 3, p = id & 7;
            int srcc = (p ^ (r & 7)) * 8;
            gload16(A + (size_t)(row0 + r)*lda + kt + srcc, &lA[buf][r*64 + p*8]);
        }
        #pragma unroll
        for (int is=0; is<4; ++is){
            int id = tid + is*512;
            int r = id >> 3, p = id & 7;
            int srcc = (p ^ (r & 7)) * 8;
            gload16(Wt + (size_t)(col0 + r)*K + kt + srcc, &lB[buf][r*64 + p*8]);
        }
    };

    const int NT = K >> 6;
    stage(0, 0);
    for (int t2 = 0; t2 < NT; ++t2){
        int cur = t2 & 1;
        if (t2 + 1 < NT){
            stage(cur ^ 1, (t2+1) << 6);
            asm volatile("s_waitcnt vmcnt(8)" ::: "memory");
        } else {
            asm volatile("s_waitcnt vmcnt(0)" ::: "memory");
        }
        __builtin_amdgcn_s_barrier();
        __builtin_amdgcn_sched_barrier(0);
        __builtin_amdgcn_s_setprio(1);
        #pragma unroll
        for (int h=0; h<2; ++h){
            bh8 af[8], bf_[4];
            #pragma unroll
            for (int i=0;i<8;i++){
                int row = wr*128 + i*16 + (lane & 15);
                int pc = (h*4 + (lane >> 4)) ^ (row & 7);
                af[i] = *(const bh8*)&lA[cur][row*64 + pc*8];
            }
            #pragma unroll
            for (int j=0;j<4;j++){
                int row = wc*64 + j*16 + (lane & 15);
                int pc = (h*4 + (lane >> 4)) ^ (row & 7);
                bf_[j] = *(const bh8*)&lB[cur][row*64 + pc*8];
            }
            #pragma unroll
            for (int i=0;i<8;i++)
                #pragma unroll
                for (int j=0;j<4;j++)
                    acc[i][j] = __builtin_amdgcn_mfma_f32_16x16x32_bf16(af[i], bf_[j], acc[i][j], 0, 0, 0);
        }
        __builtin_amdgcn_s_setprio(0);
        __builtin_amdgcn_sched_barrier(0);
        __builtin_amdgcn_s_barrier();
    }

    #pragma unroll
    for (int i=0;i<8;i++){
        int rr = row0 + wr*128 + i*16 + ((lane >> 4) << 2);
        #pragma unroll
        for (int j=0;j<4;j++){
            int cc = col0 + wc*64 + j*16 + (lane & 15);
            float bv = bias[cc];
            #pragma unroll
            for (int q=0;q<4;q++){
                int r = rr + q;
                float t = acc[i][j][q] + bv;
                if (ACT==2){
                    if (addbuf) t += addbuf[(size_t)r*512 + cc];
                    Of[(size_t)r*ldc + cc] = t;
                } else {
                    if (ACT==1) t = geluf(t);
                    Ob[(size_t)r*ldc + cc] = f2b(t);
                }
            }
        }
    }
}

// fused first-level GEMM: BK=32 2-phase + 4-chunk XOR swizzle. M=2688.
__global__ __launch_bounds__(256, 2)
void fgemm_k(const ushort* __restrict__ A, int lda, const ushort* __restrict__ Wt,
             const float* __restrict__ bs0, const float* __restrict__ bs1,
             const float* __restrict__ bs2, const float* __restrict__ bs3,
             const float* __restrict__ bs4, const float* __restrict__ bs5,
             ushort* __restrict__ o0, ushort* __restrict__ o1p, ushort* __restrict__ o2p,
             ushort* __restrict__ o3p, ushort* __restrict__ o4p,
             ushort* __restrict__ Qc, ushort* __restrict__ Qs,
             const float* __restrict__ omsc, const float* __restrict__ magscp, int K)
{
    __shared__ ushort lA[2][128*32];
    __shared__ ushort lB[2][128*32];
    const int tid = threadIdx.x, lane = tid & 63, w = tid >> 6;
    const int wr = w >> 1, wc = w & 1;
    const int nbx = gridDim.x;
    const int wg = xcd_swz(blockIdx.y*nbx + blockIdx.x, nbx*gridDim.y);
    const int row0 = (wg / nbx) * 128, col0 = (wg % nbx) * 128;

    const int srow = w*32 + (lane >> 2);
    const int sch  = lane & 3;
    const int scolA = (sch ^ (srow & 3)) * 8;
    const ushort* gA0 = A  + (size_t)(row0 + srow)      * lda + scolA;
    const ushort* gA1 = A  + (size_t)(row0 + srow + 16) * lda + scolA;
    const ushort* gB0 = Wt + (size_t)(col0 + srow)      * K   + scolA;
    const ushort* gB1 = Wt + (size_t)(col0 + srow + 16) * K   + scolA;
    const int d0 = srow*32 + sch*8, d1 = (srow+16)*32 + sch*8;

    f4 zero4 = {0.f,0.f,0.f,0.f};
    f4 acc[4][4];
    #pragma unroll
    for (int i=0;i<4;i++)
        #pragma unroll
        for (int j=0;j<4;j++) acc[i][j] = zero4;

    const int fr = lane & 15;
    const int pcr = (((lane >> 4) ^ (fr & 3))) * 8;
    gload16(gA0, &lA[0][d0]); gload16(gA1, &lA[0][d1]);
    gload16(gB0, &lB[0][d0]); gload16(gB1, &lB[0][d1]);
    __syncthreads();
    int cur = 0;
    for (int kt = 0; kt < K; kt += 32) {
        int nxt = cur ^ 1;
        if (kt + 32 < K) {
            gload16(gA0 + kt + 32, &lA[nxt][d0]); gload16(gA1 + kt + 32, &lA[nxt][d1]);
            gload16(gB0 + kt + 32, &lB[nxt][d0]); gload16(gB1 + kt + 32, &lB[nxt][d1]);
        }
        bh8 af[4], bfr[4];
        #pragma unroll
        for (int i=0;i<4;i++){
            af[i]  = *(const bh8*)&lA[cur][(wr*64 + i*16 + fr)*32 + pcr];
            bfr[i] = *(const bh8*)&lB[cur][(wc*64 + i*16 + fr)*32 + pcr];
        }
        #pragma unroll
        for (int i=0;i<4;i++)
            #pragma unroll
            for (int j=0;j<4;j++)
                acc[i][j] = __builtin_amdgcn_mfma_f32_16x16x32_bf16(af[i], bfr[j], acc[i][j], 0, 0, 0);
        __syncthreads();
        cur = nxt;
    }

    const int seg = col0 >> 9;
    if (seg == 5) {
        #pragma unroll
        for (int i=0;i<4;i++){
            int rr = row0 + wr*64 + i*16 + ((lane >> 4) << 2);
            #pragma unroll
            for (int j=0;j<4;j++){
                int lcc = (col0 - 2560) + wc*64 + j*16 + (lane & 15);
                float bv = bs5[lcc];
                #pragma unroll
                for (int q=0;q<4;q++){
                    int r = rr + q;
                    float ph = tanhf_fast(acc[i][j][q] + bv)*PI_F;
                    Qc[(size_t)r*128 + lcc] = f2b(__cosf(ph));
                    Qs[(size_t)r*128 + lcc] = f2b(__sinf(ph));
                }
            }
        }
        return;
    }
    const float* bias = seg==0?bs0: seg==1?bs1: seg==2?bs2: seg==3?bs3: bs4;
    ushort* dst = seg==0?o0: seg==1?o1p: seg==2?o2p: seg==3?o3p: o4p;
    float msc = fabsf(*magscp);
    #pragma unroll
    for (int i=0;i<4;i++){
        int rr = row0 + wr*64 + i*16 + ((lane >> 4) << 2);
        #pragma unroll
        for (int j=0;j<4;j++){
            int cc = col0 + wc*64 + j*16 + (lane & 15);
            int lcc = cc & 511;
            float bv = bias[lcc];
            float csc = (seg==0) ? fabsf(omsc[lcc]) : 1.0f;
            #pragma unroll
            for (int q=0;q<4;q++){
                int r = rr + q;
                float t = acc[i][j][q] + bv;
                if (seg==1)      t = msc/(1.0f+__expf(-t));
                else if (seg==3) t = geluf(t);
                else             t *= csc;
                dst[(size_t)r*512 + lcc] = f2b(t);
            }
        }
    }
}

// dual-A GEMM: BK=32 2-phase + 4-chunk swizzle. M=640, K=512.
__global__ __launch_bounds__(256, 2)
void mgemm_k(const ushort* __restrict__ Apos, const ushort* __restrict__ Ask,
             const ushort* __restrict__ Wm1o, const ushort* __restrict__ Wsk2,
             const float* __restrict__ bm1o, const float* __restrict__ bsk2,
             ushort* __restrict__ planes, ushort* __restrict__ Kc, ushort* __restrict__ Ks)
{
    __shared__ ushort lA[2][128*32];
    __shared__ ushort lB[2][128*32];
    const int tid = threadIdx.x, lane = tid & 63, w = tid >> 6;
    const int wr = w >> 1, wc = w & 1;
    const int nbx = gridDim.x;
    const int wg = xcd_swz(blockIdx.y*nbx + blockIdx.x, nbx*gridDim.y);
    const int row0 = (wg / nbx) * 128, col0 = (wg % nbx) * 128;
    const int seg = col0 >> 9;
    const ushort* A  = seg ? Ask  : Apos;
    const ushort* Wt = seg ? Wsk2 : Wm1o;
    const int wcol0 = seg ? (col0 - 512) : col0;
    const int K = 512;

    const int srow = w*32 + (lane >> 2);
    const int sch  = lane & 3;
    const int scolA = (sch ^ (srow & 3)) * 8;
    const ushort* gA0 = A  + (size_t)(row0 + srow)       * 512 + scolA;
    const ushort* gA1 = A  + (size_t)(row0 + srow + 16)  * 512 + scolA;
    const ushort* gB0 = Wt + (size_t)(wcol0 + srow)      * 512 + scolA;
    const ushort* gB1 = Wt + (size_t)(wcol0 + srow + 16) * 512 + scolA;
    const int d0 = srow*32 + sch*8, d1 = (srow+16)*32 + sch*8;

    f4 zero4 = {0.f,0.f,0.f,0.f};
    f4 acc[4][4];
    #pragma unroll
    for (int i=0;i<4;i++)
        #pragma unroll
        for (int j=0;j<4;j++) acc[i][j] = zero4;

    const int fr = lane & 15;
    const int pcr = (((lane >> 4) ^ (fr & 3))) * 8;
    gload16(gA0, &lA[0][d0]); gload16(gA1, &lA[0][d1]);
    gload16(gB0, &lB[0][d0]); gload16(gB1, &lB[0][d1]);
    __syncthreads();
    int cur = 0;
    for (int kt = 0; kt < K; kt += 32) {
        int nxt = cur ^ 1;
        if (kt + 32 < K) {
            gload16(gA0 + kt + 32, &lA[nxt][d0]); gload16(gA1 + kt + 32, &lA[nxt][d1]);
            gload16(gB0 + kt + 32, &lB[nxt][d0]); gload16(gB1 + kt + 32, &lB[nxt][d1]);
        }
        bh8 af[4], bfr[4];
        #pragma unroll
        for (int i=0;i<4;i++){
            af[i]  = *(const bh8*)&lA[cur][(wr*64 + i*16 + fr)*32 + pcr];
            bfr[i] = *(const bh8*)&lB[cur][(wc*64 + i*16 + fr)*32 + pcr];
        }
        #pragma unroll
        for (int i=0;i<4;i++)
            #pragma unroll
            for (int j=0;j<4;j++)
                acc[i][j] = __builtin_amdgcn_mfma_f32_16x16x32_bf16(af[i], bfr[j], acc[i][j], 0, 0, 0);
        __syncthreads();
        cur = nxt;
    }

    #pragma unroll
    for (int i=0;i<4;i++){
        int rr = row0 + wr*64 + i*16 + ((lane >> 4) << 2);
        #pragma unroll
        for (int j=0;j<4;j++){
            int cc = col0 + wc*64 + j*16 + (lane & 15);
            #pragma unroll
            for (int q=0;q<4;q++){
                int r = rr + q;
                if (seg == 0){
                    planes[(size_t)r*2048 + cc] = f2b(acc[i][j][q] + bm1o[cc]);
                } else {
                    int lcc = cc - 512;
                    float ph = tanhf_fast(acc[i][j][q] + bsk2[lcc])*PI_F;
                    Kc[(size_t)r*128 + lcc] = f2b(__cosf(ph));
                    Ks[(size_t)r*128 + lcc] = f2b(__sinf(ph));
                }
            }
        }
    }
}

// all weight transposes in ONE dispatch
struct WtArgs {
    const float* src[12];
    ushort* dst[12];
    int K[12], M[12], t0[13];
};
__global__ __launch_bounds__(256)
void wtall_k(WtArgs a)
{
    __shared__ float tile[32][33];
    int bb = blockIdx.x;
    int j = 0;
    while (bb >= a.t0[j+1]) ++j;
    int tt = bb - a.t0[j];
    int K = a.K[j], M = a.M[j];
    int mt = M >> 5;
    int kb = (tt / mt) * 32, mb = (tt % mt) * 32;
    const float* W = a.src[j]; ushort* Wt = a.dst[j];
    int tx = threadIdx.x & 31, ty = threadIdx.x >> 5;
    #pragma unroll
    for (int i = ty; i < 32; i += 8)
        tile[i][tx] = W[(size_t)(kb+i)*M + mb+tx];
    __syncthreads();
    #pragma unroll
    for (int i = ty; i < 32; i += 8)
        Wt[(size_t)(mb+i)*K + kb+tx] = f2b(tile[tx][i]);
}

// fconv: fp32 x -> bf16 xctx cols 0..511 AND chunk sums csX (s1a's x half fused)
__global__ __launch_bounds__(256)
void fconv_k(const float* __restrict__ in, ushort* __restrict__ xctx,
             float* __restrict__ csX)
{
    int bc = blockIdx.x;                  // NB*NC chunks
    int t = threadIdx.x;
    int d = t*2;
    size_t row0 = (size_t)bc * CL;        // rows contiguous: b*L + c*CL == bc*CL
    float s0=0.f, s1=0.f;
    for (int l=0;l<CL;l++){
        float2 v = *(const float2*)(in + (row0+l)*D_ + d);
        ushort h0 = f2b(v.x), h1 = f2b(v.y);
        xctx[(row0+l)*1024 + d]   = h0;
        xctx[(row0+l)*1024 + d+1] = h1;
        s0 += b2f(h0); s1 += b2f(h1);
    }
    csX[(size_t)bc*512 + d]   = s0;
    csX[(size_t)bc*512 + d+1] = s1;
}

// ---------------- s1 scans ----------------
// omega chunk sums only (x half lives in fconv now)
__global__ __launch_bounds__(256)
void s1a_k(const ushort* __restrict__ omega, float* __restrict__ csA)
{
    int bid = blockIdx.x;                 // NB*NC*2
    int bc = bid >> 1, dg = bid & 1;
    int d = dg*256 + threadIdx.x;
    size_t base = ((size_t)bc*CL)*D_ + d;
    float sA=0.f;
    for (int l=0;l<CL;l++) sA += b2f(omega[base + (size_t)l*D_]);
    csA[(size_t)bc*D_ + d] = sA;
}

// merged aux: blocks [0,2*nb2): exclusive prefix for csA/csX (buffer-parallel);
// blocks [2*nb2, 2*nb2+NB): gate cumsum -> rinv
__global__ __launch_bounds__(256)
void aux1_k(float* __restrict__ csA, float* __restrict__ csX,
            const float* __restrict__ sgate, float* __restrict__ rinv, int nb2)
{
    __shared__ float wsum[4];
    __shared__ float carry;
    int bb = blockIdx.x, t = threadIdx.x;
    if (bb < 2*nb2){
        float* buf = (bb < nb2) ? csA : csX;
        int gb = (bb < nb2) ? bb : bb - nb2;
        int tt = gb*256 + t;
        int b = tt >> 9, d = tt & 511;
        float* p = buf + ((size_t)b*NC)*D_ + d;
        float run=0.f;
        for (int c=0;c<NC;c++){
            float v = p[(size_t)c*D_];
            p[(size_t)c*D_] = run;
            run += v;
        }
        return;
    }
    int b = bb - 2*nb2;
    int lane = t & 63, wave = t >> 6;
    if (t == 0) carry = 0.f;
    __syncthreads();
    for (int s = 0; s < L_/256; s++){
        float v = sgate[(size_t)b*L_ + s*256 + t];
        float sc = v;
        #pragma unroll
        for (int off=1; off<64; off<<=1){
            float u = __shfl_up(sc, off, 64);
            if (lane >= off) sc += u;
        }
        if (lane == 63) wsum[wave] = sc;
        __syncthreads();
        float woff = carry;
        for (int w2 = 0; w2 < wave; w2++) woff += wsum[w2];
        float inc = sc + woff;
        rinv[(size_t)b*L_ + s*256 + t] = rsqrtf(fmaxf(inc, 1.0f));
        __syncthreads();
        if (t == 255) carry = inc;
        __syncthreads();
    }
}

// buffer-parallel exclusive prefix for 3 [NB*NC][512] buffers; grid = 3*nb2
__global__ void prefix_k(float* a, float* b2v, float* c3, int nb2)
{
    int bb = blockIdx.x;
    float* bufs[3] = {a,b2v,c3};
    float* buf = bufs[bb / nb2];
    int gb = bb % nb2;
    int tt = gb*256 + threadIdx.x;
    int b = tt >> 9, d = tt & 511;
    float* p = buf + ((size_t)b*NC)*D_ + d;
    float run=0.f;
    for (int c=0;c<NC;c++){
        float v = p[(size_t)c*D_];
        p[(size_t)c*D_] = run;
        run += v;
    }
}

__global__ __launch_bounds__(256)
void s1c_k(const ushort* __restrict__ omega, const ushort* __restrict__ phi_init,
           const ushort* __restrict__ magn, const ushort* __restrict__ v1,
           const float* __restrict__ csA, const float* __restrict__ csX,
           ushort* __restrict__ cphi, ushort* __restrict__ sphi, ushort* __restrict__ xctx,
           float* __restrict__ csM, float* __restrict__ csC, float* __restrict__ csS)
{
    int bid = blockIdx.x;
    int b = bid >> 7; int rem = bid & 127;
    int dg = rem & 1, c = rem >> 1;
    int d = dg*256 + threadIdx.x;
    size_t ci = ((size_t)b*NC + c)*D_ + d;
    float phiacc = csA[ci], xacc = csX[ci];
    float sM=0.f,sC=0.f,sS=0.f;
    size_t xrow = (size_t)b*L_ + (size_t)c*CL;
    size_t base = xrow*D_ + d;
    for (int l=0;l<CL;l++){
        size_t idx = base + (size_t)l*D_;
        phiacc += b2f(omega[idx]);
        float ph = b2f(phi_init[idx]) + phiacc;
        float spv = __sinf(ph), cpv = __cosf(ph);
        cphi[idx] = f2b(cpv); sphi[idx] = f2b(spv);
        xacc += b2f(xctx[(xrow + l)*1024 + d]);
        xctx[(xrow + l)*1024 + 512 + d] = f2b(__fdividef(xacc, (float)(c*CL + l + 1)));
        float m = b2f(magn[idx]); sM += m;
        float wv = m * b2f(v1[idx]);
        sC = fmaf(wv, cpv, sC); sS = fmaf(wv, spv, sS);
    }
    csM[ci]=sM; csC[ci]=sC; csS[ci]=sS;
}

__global__ __launch_bounds__(256)
void s1e_k(const ushort* __restrict__ magn, const ushort* __restrict__ v1,
           const ushort* qoff, const ushort* __restrict__ cphi, const ushort* __restrict__ sphi,
           const float* __restrict__ csM, const float* __restrict__ csC,
           const float* __restrict__ csS, ushort* pos_ret)
{
    int bid = blockIdx.x;
    int b = bid >> 7; int rem = bid & 127;
    int dg = rem & 1, c = rem >> 1;
    int d = dg*256 + threadIdx.x;
    size_t ci = ((size_t)b*NC + c)*D_ + d;
    float mA=csM[ci], cA=csC[ci], sA=csS[ci];
    size_t base = ((size_t)b*L_ + (size_t)c*CL)*D_ + d;
    for (int l=0;l<CL;l++){
        size_t idx = base + (size_t)l*D_;
        float m = b2f(magn[idx]); mA += m;
        float wv = m * b2f(v1[idx]);
        float cp = b2f(cphi[idx]), sp = b2f(sphi[idx]);
        cA = fmaf(wv, cp, cA); sA = fmaf(wv, sp, sA);
        float rs = rsqrtf(mA + 1e-8f);
        float qo = b2f(qoff[idx]);
        float sq = __sinf(qo), cq = __cosf(qo);
        float cosq = cp*cq - sp*sq;
        float sinq = sp*cq + cp*sq;
        pos_ret[idx] = f2b((cA*cosq + sA*sinq) * rs * 0.04419417382415922f);
    }
}

__global__ __launch_bounds__(256)
void vencsg_k(const ushort* __restrict__ xctx, const float* __restrict__ Wv,
              const float* __restrict__ bv, const float* __restrict__ Wg,
              const float* __restrict__ bg,
              ushort* __restrict__ gvb, float* __restrict__ sgate)
{
    int gw = (int)((blockIdx.x*(size_t)blockDim.x + threadIdx.x) >> 6);
    int lane = threadIdx.x & 63;
    const ushort* xr = xctx + (size_t)gw*1024;
    float pv[8] = {0,0,0,0,0,0,0,0}; float pg = 0.f;
    #pragma unroll
    for (int j=0;j<8;j++){
        int k = lane + 64*j;
        float xv = b2f(xr[k]);
        #pragma unroll
        for (int v=0;v<8;v++) pv[v] = fmaf(xv, Wv[k*8+v], pv[v]);
        pg = fmaf(xv, Wg[k], pg);
    }
    #pragma unroll
    for (int off=32; off>0; off>>=1){
        #pragma unroll
        for (int v=0;v<8;v++) pv[v] += __shfl_down(pv[v], off, 64);
        pg += __shfl_down(pg, off, 64);
    }
    if (lane==0){
        float sg = 1.0f/(1.0f+__expf(-(pg + bg[0])));
        #pragma unroll
        for (int v=0;v<8;v++) gvb[(size_t)gw*8+v] = f2b((pv[v] + bv[v]) * sg);
        sgate[gw] = sg;
    }
}

__global__ __launch_bounds__(256)
void kvsum_k(const ushort* __restrict__ Kc, const ushort* __restrict__ Ks,
             const ushort* __restrict__ gvb, float* __restrict__ csKV)
{
    int bid = blockIdx.x;
    int b = bid >> 6, c = bid & 63;
    int t = threadIdx.x; int p = t & 127; int v0 = (t>>7)*4;
    size_t row0 = (size_t)b*L_ + (size_t)c*64;
    float ac[4]={0,0,0,0}, as[4]={0,0,0,0};
    for (int l=0;l<64;l++){
        size_t r = row0 + l;
        float kc = b2f(Kc[r*(size_t)P_ + p]);
        float ks = b2f(Ks[r*(size_t)P_ + p]);
        #pragma unroll
        for (int j=0;j<4;j++){
            float gv = b2f(gvb[r*(size_t)V_ + v0 + j]);
            ac[j] = fmaf(kc, gv, ac[j]);
            as[j] = fmaf(ks, gv, as[j]);
        }
    }
    float* base = csKV + ((size_t)b*64 + c)*2048;
    #pragma unroll
    for (int j=0;j<4;j++){
        base[p*V_ + v0 + j] = ac[j];
        base[1024 + p*V_ + v0 + j] = as[j];
    }
}

__global__ void kvpfx_k(float* __restrict__ csKV)
{
    int t = blockIdx.x*blockDim.x + threadIdx.x;
    int b = t >> 11, si = t & 2047;
    float* ptr = csKV + ((size_t)b*64)*2048 + si;
    float run=0.f;
    for (int c=0;c<64;c++){
        float v = ptr[(size_t)c*2048];
        ptr[(size_t)c*2048] = run;
        run += v;
    }
}

__global__ __launch_bounds__(256)
void kv2_k(const ushort* __restrict__ Qc, const ushort* __restrict__ Qs,
           const ushort* __restrict__ Kc, const ushort* __restrict__ Ks,
           const ushort* __restrict__ gvb, const float* __restrict__ rinv,
           const float* __restrict__ csKV, float* __restrict__ kvret)
{
    __shared__ ushort sS[64][66];
    __shared__ float sM[2048];
    __shared__ float sgv[64][8];
    int tile = blockIdx.x, b = blockIdx.y;
    int t = threadIdx.x, lane = t & 63, w = t >> 6;
    int wr = w >> 1, wc = w & 1;
    size_t row0 = (size_t)b*L_ + (size_t)tile*64;
    const float* kvb = csKV + ((size_t)b*64 + tile)*2048;
    #pragma unroll
    for (int k=0;k<8;k++) sM[t + k*256] = kvb[t + k*256];
    #pragma unroll
    for (int k=0;k<2;k++){
        int idx = t + k*256; int l = idx >> 3, v = idx & 7;
        sgv[l][v] = b2f(gvb[(row0 + l)*(size_t)V_ + v]);
    }
    f4 zero4 = {0.f,0.f,0.f,0.f};
    f4 acc[2][2];
    #pragma unroll
    for (int i=0;i<2;i++)
        #pragma unroll
        for (int j=0;j<2;j++) acc[i][j] = zero4;
    #pragma unroll
    for (int ks=0; ks<8; ks++){
        const ushort* Ab = (ks<4) ? Qc : Qs;
        const ushort* Bb = (ks<4) ? Kc : Ks;
        int kb = (ks&3)*32 + (lane>>4)*8;
        bh8 af[2], bfr[2];
        #pragma unroll
        for (int i=0;i<2;i++)
            af[i] = *(const bh8*)(Ab + (row0 + wr*32 + i*16 + (lane&15))*(size_t)P_ + kb);
        #pragma unroll
        for (int j=0;j<2;j++)
            bfr[j] = *(const bh8*)(Bb + (row0 + wc*32 + j*16 + (lane&15))*(size_t)P_ + kb);
        #pragma unroll
        for (int i=0;i<2;i++)
            #pragma unroll
            for (int j=0;j<2;j++)
                acc[i][j] = __builtin_amdgcn_mfma_f32_16x16x32_bf16(af[i], bfr[j], acc[i][j], 0, 0, 0);
    }
    #pragma unroll
    for (int i=0;i<2;i++){
        #pragma unroll
        for (int j=0;j<2;j++){
            int cc = wc*32 + j*16 + (lane & 15);
            #pragma unroll
            for (int q=0;q<4;q++){
                int lr = wr*32 + i*16 + ((lane>>4)<<2) + q;
                sS[lr][cc] = f2b((cc <= lr) ? acc[i][j][q] : 0.f);
            }
        }
    }
    __syncthreads();
    int l = t & 63, vh = t >> 6; int v0 = vh*2;
    const ushort* qcr = Qc + (row0 + l)*(size_t)P_;
    const ushort* qsr = Qs + (row0 + l)*(size_t)P_;
    float a0=0.f, a1=0.f;
    #pragma unroll
    for (int pc=0; pc<16; pc++){
        bh8 qc8 = *(const bh8*)(qcr + pc*8);
        bh8 qs8 = *(const bh8*)(qsr + pc*8);
        #pragma unroll
        for (int e=0;e<8;e++){
            int p = pc*8+e;
            float qc = b2f((ushort)qc8[e]), qs = b2f((ushort)qs8[e]);
            a0 += qc*sM[p*8+v0]   + qs*sM[1024+p*8+v0];
            a1 += qc*sM[p*8+v0+1] + qs*sM[1024+p*8+v0+1];
        }
    }
    for (int c=0;c<64;c++){
        float sv = b2f(sS[l][c]);
        a0 = fmaf(sv, sgv[c][v0],   a0);
        a1 = fmaf(sv, sgv[c][v0+1], a1);
    }
    float rn = rinv[row0 + l] * 0.08838834764831845f;
    kvret[(row0+l)*(size_t)V_ + v0]   = a0*rn;
    kvret[(row0+l)*(size_t)V_ + v0+1] = a1*rn;
}

// combined + LN; kv_out in-register from kvret; x from xctx bf16
__global__ __launch_bounds__(256)
void cmb_k(const ushort* __restrict__ xctx, const ushort* __restrict__ cphi,
           const ushort* __restrict__ sphi,
           const float* __restrict__ kvret, const float* __restrict__ Wkvo,
           const float* __restrict__ bkvo,
           const float* __restrict__ ln_g, const float* __restrict__ ln_b,
           ushort* pl)
{
    __shared__ float red[8];
    __shared__ float kvv[8];
    int n = blockIdx.x; int t = threadIdx.x;
    int wave = t>>6, lane = t&63;
    if (t < 8) kvv[t] = kvret[(size_t)n*8 + t];
    __syncthreads();
    float v_[8]; float sum=0.f, sumsq=0.f;
    #pragma unroll
    for (int i=0;i<8;i++){
        int cidx = t + i*256;
        int seg = cidx >> 9, cc = cidx & 511;
        float v;
        if (seg == 0) v = b2f(pl[(size_t)n*2048 + cidx]);
        else if (seg == 1) {
            v = bkvo[cc];
            #pragma unroll
            for (int vv=0; vv<8; vv++) v = fmaf(kvv[vv], Wkvo[vv*512 + cc], v);
        } else {
            size_t id = (size_t)n*D_ + cc;
            v = b2f(xctx[(size_t)n*1024 + cc]) * b2f((seg==2) ? cphi[id] : sphi[id]);
        }
        v_[i]=v; sum += v; sumsq = fmaf(v,v,sumsq);
    }
    #pragma unroll
    for (int off=32; off>0; off>>=1){
        sum += __shfl_xor(sum, off, 64);
        sumsq += __shfl_xor(sumsq, off, 64);
    }
    if (lane==0){ red[wave]=sum; red[wave+4]=sumsq; }
    __syncthreads();
    float s = red[0]+red[1]+red[2]+red[3];
    float q = red[4]+red[5]+red[6]+red[7];
    float mu = s * (1.0f/2048.0f);
    float var = q * (1.0f/2048.0f) - mu*mu;
    float rstd = rsqrtf(var + 1e-5f);
    #pragma unroll
    for (int i=0;i<8;i++){
        int cidx = t + i*256;
        float h = (v_[i]-mu)*rstd*ln_g[cidx] + ln_b[cidx];
        pl[(size_t)n*2048 + cidx] = f2b(h);
    }
}

__global__ void copyx_k(const float* __restrict__ x, float* __restrict__ out, size_t n)
{
    size_t i = (size_t)blockIdx.x*256 + threadIdx.x;
    if (i < n) out[i] = x[i];
}

// ---------------- host ----------------
struct WS {
    ushort *wt_fused,*wt_pi2,*wt_sk1,*wt_sk2,*wt_m1o,*wt_o1,*wt_o2;
    ushort *xctx, *pool;
    ushort *Qc,*Qs,*Kc,*Ks,*gvb,*cphi,*sphi;
    float *sgate,*rinv,*kvret;
    float *csA,*csX,*csM,*csC,*csS,*csKV;
};

static size_t ws_layout(WS& w, char* base, int NB)
{
    size_t off = 0;
    auto al = [&](size_t bytes)->char* {
        char* p = base + off; off = (off + bytes + 255) & ~(size_t)255; return p;
    };
    size_t R = (size_t)NB * L_;
    w.wt_fused=(ushort*)al((size_t)2688*512*2);
    w.wt_pi2 =(ushort*)al(512*512*2);
    w.wt_sk1 =(ushort*)al((size_t)512*1024*2); w.wt_sk2=(ushort*)al(128*512*2);
    w.wt_m1o =(ushort*)al(512*512*2);
    w.wt_o1  =(ushort*)al((size_t)1024*2048*2); w.wt_o2=(ushort*)al((size_t)512*1024*2);
    w.xctx=(ushort*)al(R*1024*2);
    w.pool=(ushort*)al(R*512*2*6);
    w.Qc=(ushort*)al(R*128*2); w.Qs=(ushort*)al(R*128*2);
    w.Kc=(ushort*)al(R*128*2); w.Ks=(ushort*)al(R*128*2);
    w.gvb=(ushort*)al(R*8*2);
    w.cphi=(ushort*)al(R*512*2); w.sphi=(ushort*)al(R*512*2);
    w.sgate=(float*)al(R*4); w.rinv=(float*)al(R*4); w.kvret=(float*)al(R*8*4);
    w.csA=(float*)al((size_t)NB*NC*512*4); w.csX=(float*)al((size_t)NB*NC*512*4);
    w.csM=(float*)al((size_t)NB*NC*512*4); w.csC=(float*)al((size_t)NB*NC*512*4);
    w.csS=(float*)al((size_t)NB*NC*512*4);
    w.csKV=(float*)al((size_t)NB*64*2048*4);
    return off;
}

extern "C" void kernel_launch(void* const* d_in, const int* in_sizes, int n_in,
                              void* d_out, int out_size, void* d_ws, size_t ws_size,
                              hipStream_t stream)
{
    const float* x        =(const float*)d_in[0];
    const float* W_omega  =(const float*)d_in[1];  const float* b_omega=(const float*)d_in[2];
    const float* omega_sc =(const float*)d_in[3];
    const float* W_pi1    =(const float*)d_in[4];  const float* b_pi1 =(const float*)d_in[5];
    const float* W_pi2    =(const float*)d_in[6];  const float* b_pi2 =(const float*)d_in[7];
    const float* W_m1v    =(const float*)d_in[8];  const float* b_m1v =(const float*)d_in[9];
    const float* W_m1o    =(const float*)d_in[10]; const float* b_m1o =(const float*)d_in[11];
    const float* W_mag    =(const float*)d_in[12]; const float* b_mag =(const float*)d_in[13];
    const float* mag_sc   =(const float*)d_in[14];
    const float* W_qoff   =(const float*)d_in[15]; const float* b_qoff=(const float*)d_in[16];
    const float* W_kenc   =(const float*)d_in[17]; const float* b_kenc=(const float*)d_in[18];
    const float* W_venc   =(const float*)d_in[19]; const float* b_venc=(const float*)d_in[20];
    const float* W_sk1    =(const float*)d_in[21]; const float* b_sk1 =(const float*)d_in[22];
    const float* W_sk2    =(const float*)d_in[23]; const float* b_sk2 =(const float*)d_in[24];
    const float* W_sg     =(const float*)d_in[25]; const float* b_sg  =(const float*)d_in[26];
    const float* W_kvo    =(const float*)d_in[27]; const float* b_kvo =(const float*)d_in[28];
    const float* ln_g     =(const float*)d_in[29]; const float* ln_b  =(const float*)d_in[30];
    const float* W_o1     =(const float*)d_in[31]; const float* b_o1  =(const float*)d_in[32];
    const float* W_o2     =(const float*)d_in[33]; const float* b_o2  =(const float*)d_in[34];
    float* out = (float*)d_out;

    char* wsb = (char*)d_ws;
    WS w;
    int NB = 4;
    if (ws_layout(w, wsb, 4) > ws_size) {
        NB = 2;
        if (ws_layout(w, wsb, 2) > ws_size) {
            NB = 1;
            if (ws_layout(w, wsb, 1) > ws_size) {
                copyx_k<<<dim3((unsigned)(((size_t)N_*D_ + 255)/256)), dim3(256), 0, stream>>>(x, out, (size_t)N_*D_);
                return;
            }
        }
    }

    dim3 blk(256);
    WtArgs wa;
    const float* srcs[12] = {W_omega, W_mag, W_m1v, W_pi1, W_qoff, W_kenc,
                             W_pi2, W_sk1, W_sk2, W_m1o, W_o1, W_o2};
    ushort* dsts[12] = {w.wt_fused + (size_t)0*512*512, w.wt_fused + (size_t)1*512*512,
                        w.wt_fused + (size_t)2*512*512, w.wt_fused + (size_t)3*512*512,
                        w.wt_fused + (size_t)4*512*512, w.wt_fused + (size_t)5*512*512,
                        w.wt_pi2, w.wt_sk1, w.wt_sk2, w.wt_m1o, w.wt_o1, w.wt_o2};
    int Ks_[12] = {512,512,512,512,512,512, 512,1024,512,512,2048,1024};
    int Ms_[12] = {512,512,512,512,512,128, 512, 512,128,512,1024, 512};
    int cum = 0;
    for (int j = 0; j < 12; ++j){
        wa.src[j]=srcs[j]; wa.dst[j]=dsts[j]; wa.K[j]=Ks_[j]; wa.M[j]=Ms_[j];
        wa.t0[j]=cum; cum += (Ks_[j]/32)*(Ms_[j]/32);
    }
    wa.t0[12]=cum;
    wtall_k<<<dim3(cum), blk, 0, stream>>>(wa);

    const int R = NB * L_;
    const size_t SL = (size_t)R * 512;
    ushort* bA = w.pool;        ushort* bB = w.pool + SL;
    ushort* bC = w.pool + 2*SL; ushort* bD = w.pool + 3*SL;
    ushort* bE = w.pool + 4*SL; ushort* bF = w.pool + 5*SL;
    ushort* planes = w.pool;               // [R][2048] = slots 0-3
    ushort* h1 = w.pool + 4*SL;            // [R][1024] = slots 4-5

    #define DGEMM(ACT,A,lda,Wt_,bias_,Ob_,Of_,ldc,K_,M_,add_) \
        dgemm_k<ACT><<<dim3((M_)/128, R/128), blk, 0, stream>>>(A,lda,Wt_,bias_,Ob_,Of_,ldc,K_,add_)
    #define EGEMM(ACT,A,lda,Wt_,bias_,Ob_,Of_,ldc,K_,M_,add_) \
        egemm_k<ACT><<<dim3((M_)/256, R/256), dim3(512), 0, stream>>>(A,lda,Wt_,bias_,Ob_,Of_,ldc,K_,add_)

    for (int g = 0; g < B_/NB; ++g) {
        const float* xg = x + (size_t)g*NB*LD;
        float* outg = out + (size_t)g*NB*LD;

        fconv_k<<<dim3(NB*NC), blk, 0, stream>>>(xg, w.xctx, w.csX);   // x->bf16 + csX sums

        fgemm_k<<<dim3(2688/128, R/128), blk, 0, stream>>>(
            w.xctx,1024, w.wt_fused, b_omega,b_mag,b_m1v,b_pi1,b_qoff,b_kenc,
            bA,bB,bC,bD,bF, w.Qc,w.Qs, omega_sc, mag_sc, 512);
        DGEMM(0, bD,512, w.wt_pi2, b_pi2, bE,(float*)0, 512, 512,512, (const float*)0);  // phi_init -> bE
        vencsg_k<<<dim3((unsigned)((size_t)R*64/256)), blk, 0, stream>>>(w.xctx, W_venc,b_venc, W_sg,b_sg, w.gvb, w.sgate);
        s1a_k<<<dim3(NB*NC*2), blk, 0, stream>>>(bA, w.csA);
        aux1_k<<<dim3(NB*4 + NB), blk, 0, stream>>>(w.csA, w.csX, w.sgate, w.rinv, NB*2);
        s1c_k<<<dim3(NB*NC*2), blk, 0, stream>>>(bA, bE, bB, bC, w.csA, w.csX,
                                                 w.cphi, w.sphi, w.xctx, w.csM, w.csC, w.csS);
        prefix_k<<<dim3(NB*6), blk, 0, stream>>>(w.csM, w.csC, w.csS, NB*2);
        s1e_k<<<dim3(NB*NC*2), blk, 0, stream>>>(bB, bC, bF, w.cphi, w.sphi,
                                                 w.csM, w.csC, w.csS, bF);              // bF = pos_ret

        DGEMM(1, w.xctx,1024, w.wt_sk1, b_sk1, bE,(float*)0, 512, 1024,512, (const float*)0); // sk1g -> bE
        mgemm_k<<<dim3(640/128, R/128), blk, 0, stream>>>(
            bF, bE, w.wt_m1o, w.wt_sk2, b_m1o, b_sk2, planes, w.Kc, w.Ks);

        kvsum_k<<<dim3(NB*64), blk, 0, stream>>>(w.Kc, w.Ks, w.gvb, w.csKV);
        kvpfx_k<<<dim3(NB*8), blk, 0, stream>>>(w.csKV);
        kv2_k<<<dim3(64, NB), blk, 0, stream>>>(w.Qc, w.Qs, w.Kc, w.Ks, w.gvb, w.rinv, w.csKV, w.kvret);

        cmb_k<<<dim3(R), blk, 0, stream>>>(w.xctx, w.cphi, w.sphi, w.kvret, W_kvo, b_kvo,
                                           ln_g, ln_b, planes);
        EGEMM(1, planes,2048, w.wt_o1, b_o1, h1,(float*)0, 1024, 2048,1024, (const float*)0); // h1 (256^2)
        DGEMM(2, h1,1024, w.wt_o2, b_o2, (ushort*)0,outg, 512, 1024,512, xg);                 // out
    }
    #undef DGEMM
    #undef EGEMM
}

// Round 15
// 465.138 us; speedup vs baseline: 1.0240x; 1.0240x over previous
//
#include <hip/hip_runtime.h>
#include <math.h>

#define B_ 4
#define L_ 4096
#define D_ 512
#define P_ 128
#define V_ 8
#define N_ (B_*L_)
#define NC 64
#define CL (L_/NC)
#define LD ((size_t)L_*D_)
#define PI_F 3.14159265358979323846f

typedef unsigned short ushort;
typedef __attribute__((ext_vector_type(8))) short bh8;
typedef __attribute__((ext_vector_type(4))) float f4;
typedef const __attribute__((address_space(1))) unsigned int gu32;
typedef __attribute__((address_space(3))) unsigned int lu32;

__device__ __forceinline__ float geluf(float v){
    return 0.5f*v*(1.0f+erff(v*0.7071067811865475f));
}
__device__ __forceinline__ float tanhf_fast(float x){
    return 1.0f - 2.0f/(__expf(2.0f*x)+1.0f);
}
__device__ __forceinline__ ushort f2b(float f){
    union { float f; unsigned u; } v; v.f = f;
    unsigned r = (v.u + 0x7fffu + ((v.u >> 16) & 1u)) >> 16;
    return (ushort)r;
}
__device__ __forceinline__ float b2f(ushort h){
    union { unsigned u; float f; } v; v.u = ((unsigned)h) << 16;
    return v.f;
}
__device__ __forceinline__ void gload16(const ushort* g, ushort* l){
    __builtin_amdgcn_global_load_lds((gu32*)g, (lu32*)l, 16, 0, 0);
}
__device__ __forceinline__ int xcd_swz(int orig, int nwg){
    int q8 = nwg >> 3, r8 = nwg & 7;
    int xcd = orig & 7, sub = orig >> 3;
    return (xcd < r8 ? xcd*(q8+1) : r8*(q8+1) + (xcd-r8)*q8) + sub;
}

// ===== dgemm: 128x128, BK=64, XOR swizzle, counted vmcnt(8), 2 blocks/CU
template<int ACT>
__global__ __launch_bounds__(256, 2)
void dgemm_k(const ushort* __restrict__ A, int lda,
             const ushort* __restrict__ Wt, const float* __restrict__ bias,
             ushort* __restrict__ Ob, float* __restrict__ Of,
             int ldc, int K, const float* __restrict__ addbuf)
{
    __shared__ ushort lA[2][128*64];
    __shared__ ushort lB[2][128*64];
    const int tid = threadIdx.x, lane = tid & 63, w = tid >> 6;
    const int wr = w >> 1, wc = w & 1;
    const int nbx = gridDim.x;
    const int wg = xcd_swz(blockIdx.y*nbx + blockIdx.x, nbx*gridDim.y);
    const int row0 = (wg / nbx) * 128, col0 = (wg % nbx) * 128;

    f4 zero4 = {0.f,0.f,0.f,0.f};
    f4 acc[4][4];
    #pragma unroll
    for (int i=0;i<4;i++)
        #pragma unroll
        for (int j=0;j<4;j++) acc[i][j] = zero4;

    auto stage = [&](int buf, int kt){
        #pragma unroll
        for (int is=0; is<4; ++is){
            int id = tid + is*256;
            int r = id >> 3, p = id & 7;
            int srcc = (p ^ (r & 7)) * 8;
            gload16(A + (size_t)(row0 + r)*lda + kt + srcc, &lA[buf][r*64 + p*8]);
        }
        #pragma unroll
        for (int is=0; is<4; ++is){
            int id = tid + is*256;
            int r = id >> 3, p = id & 7;
            int srcc = (p ^ (r & 7)) * 8;
            gload16(Wt + (size_t)(col0 + r)*K + kt + srcc, &lB[buf][r*64 + p*8]);
        }
    };

    const int NT = K >> 6;
    stage(0, 0);
    for (int t2 = 0; t2 < NT; ++t2){
        int cur = t2 & 1;
        if (t2 + 1 < NT){
            stage(cur ^ 1, (t2+1) << 6);
            asm volatile("s_waitcnt vmcnt(8)" ::: "memory");
        } else {
            asm volatile("s_waitcnt vmcnt(0)" ::: "memory");
        }
        __builtin_amdgcn_s_barrier();
        __builtin_amdgcn_sched_barrier(0);
        #pragma unroll
        for (int h=0; h<2; ++h){
            bh8 af[4], bf_[4];
            #pragma unroll
            for (int i=0;i<4;i++){
                int row = wr*64 + i*16 + (lane & 15);
                int pc = (h*4 + (lane >> 4)) ^ (row & 7);
                af[i] = *(const bh8*)&lA[cur][row*64 + pc*8];
            }
            #pragma unroll
            for (int j=0;j<4;j++){
                int row = wc*64 + j*16 + (lane & 15);
                int pc = (h*4 + (lane >> 4)) ^ (row & 7);
                bf_[j] = *(const bh8*)&lB[cur][row*64 + pc*8];
            }
            #pragma unroll
            for (int i=0;i<4;i++)
                #pragma unroll
                for (int j=0;j<4;j++)
                    acc[i][j] = __builtin_amdgcn_mfma_f32_16x16x32_bf16(af[i], bf_[j], acc[i][j], 0, 0, 0);
        }
        __builtin_amdgcn_sched_barrier(0);
        __builtin_amdgcn_s_barrier();
    }

    #pragma unroll
    for (int i=0;i<4;i++){
        int rr = row0 + wr*64 + i*16 + ((lane >> 4) << 2);
        #pragma unroll
        for (int j=0;j<4;j++){
            int cc = col0 + wc*64 + j*16 + (lane & 15);
            float bv = bias[cc];
            #pragma unroll
            for (int q=0;q<4;q++){
                int r = rr + q;
                float t = acc[i][j][q] + bv;
                if (ACT==2){
                    if (addbuf) t += addbuf[(size_t)r*512 + cc];
                    Of[(size_t)r*ldc + cc] = t;
                } else {
                    if (ACT==1) t = geluf(t);
                    Ob[(size_t)r*ldc + cc] = f2b(t);
                }
            }
        }
    }
}

// ===== egemm: 256x256, 8 waves, wave-tile 128x64, BK=64, 4-PHASE interleave
// (o1 only). Per K-tile: 1 vmcnt(0)+barrier; 4 phases of {ds_reads ∥ 2 stage
// issues -> sched_barrier -> setprio 16-MFMA}.
template<int ACT>
__global__ __launch_bounds__(512, 1)
void egemm_k(const ushort* __restrict__ A, int lda,
             const ushort* __restrict__ Wt, const float* __restrict__ bias,
             ushort* __restrict__ Ob, float* __restrict__ Of,
             int ldc, int K, const float* __restrict__ addbuf)
{
    __shared__ ushort lA[2][256*64];
    __shared__ ushort lB[2][256*64];
    const int tid = threadIdx.x, lane = tid & 63, w = tid >> 6;
    const int wr = w >> 2, wc = w & 3;
    const int nbx = gridDim.x;
    const int wg = xcd_swz(blockIdx.y*nbx + blockIdx.x, nbx*gridDim.y);
    const int row0 = (wg / nbx) * 256, col0 = (wg % nbx) * 256;

    f4 zero4 = {0.f,0.f,0.f,0.f};
    f4 acc[8][4];
    #pragma unroll
    for (int i=0;i<8;i++)
        #pragma unroll
        for (int j=0;j<4;j++) acc[i][j] = zero4;

    auto stageL = [&](int buf, int kt, int li){
        int id = tid + (li & 3)*512;
        int r = id >> 3, p = id & 7;
        int srcc = (p ^ (r & 7)) * 8;
        if (li < 4)
            gload16(A + (size_t)(row0 + r)*lda + kt + srcc, &lA[buf][r*64 + p*8]);
        else
            gload16(Wt + (size_t)(col0 + r)*K + kt + srcc, &lB[buf][r*64 + p*8]);
    };

    #pragma unroll
    for (int li=0; li<8; ++li) stageL(0, 0, li);

    const int NT = K >> 6;
    for (int t2 = 0; t2 < NT; ++t2){
        int cur = t2 & 1;
        asm volatile("s_waitcnt vmcnt(0)" ::: "memory");   // cur tile landed (own)
        __builtin_amdgcn_s_barrier();                      // all waves' loads landed
        bh8 bf_[4];
        #pragma unroll
        for (int ph=0; ph<4; ++ph){
            const int h = ph >> 1, q = ph & 1;
            if (q == 0){
                #pragma unroll
                for (int j=0;j<4;j++){
                    int row = wc*64 + j*16 + (lane & 15);
                    int pc = (h*4 + (lane >> 4)) ^ (row & 7);
                    bf_[j] = *(const bh8*)&lB[cur][row*64 + pc*8];
                }
            }
            bh8 af[4];
            #pragma unroll
            for (int ii=0; ii<4; ++ii){
                int i = q*4 + ii;
                int row = wr*128 + i*16 + (lane & 15);
                int pc = (h*4 + (lane >> 4)) ^ (row & 7);
                af[ii] = *(const bh8*)&lA[cur][row*64 + pc*8];
            }
            if (t2 + 1 < NT){                              // spread next-tile stage
                stageL(cur^1, (t2+1) << 6, 2*ph);
                stageL(cur^1, (t2+1) << 6, 2*ph + 1);
            }
            __builtin_amdgcn_sched_barrier(0);
            __builtin_amdgcn_s_setprio(1);
            #pragma unroll
            for (int ii=0; ii<4; ++ii)
                #pragma unroll
                for (int j=0;j<4;j++)
                    acc[q*4+ii][j] = __builtin_amdgcn_mfma_f32_16x16x32_bf16(af[ii], bf_[j], acc[q*4+ii][j], 0, 0, 0);
            __builtin_amdgcn_s_setprio(0);
            __builtin_amdgcn_sched_barrier(0);
        }
    }

    #pragma unroll
    for (int i=0;i<8;i++){
        int rr = row0 + wr*128 + i*16 + ((lane >> 4) << 2);
        #pragma unroll
        for (int j=0;j<4;j++){
            int cc = col0 + wc*64 + j*16 + (lane & 15);
            float bv = bias[cc];
            #pragma unroll
            for (int q=0;q<4;q++){
                int r = rr + q;
                float t = acc[i][j][q] + bv;
                if (ACT==2){
                    if (addbuf) t += addbuf[(size_t)r*512 + cc];
                    Of[(size_t)r*ldc + cc] = t;
                } else {
                    if (ACT==1) t = geluf(t);
                    Ob[(size_t)r*ldc + cc] = f2b(t);
                }
            }
        }
    }
}

// fused first-level GEMM: BK=32 2-phase + 4-chunk XOR swizzle. M=2688.
__global__ __launch_bounds__(256, 2)
void fgemm_k(const ushort* __restrict__ A, int lda, const ushort* __restrict__ Wt,
             const float* __restrict__ bs0, const float* __restrict__ bs1,
             const float* __restrict__ bs2, const float* __restrict__ bs3,
             const float* __restrict__ bs4, const float* __restrict__ bs5,
             ushort* __restrict__ o0, ushort* __restrict__ o1p, ushort* __restrict__ o2p,
             ushort* __restrict__ o3p, ushort* __restrict__ o4p,
             ushort* __restrict__ Qc, ushort* __restrict__ Qs,
             const float* __restrict__ omsc, const float* __restrict__ magscp, int K)
{
    __shared__ ushort lA[2][128*32];
    __shared__ ushort lB[2][128*32];
    const int tid = threadIdx.x, lane = tid & 63, w = tid >> 6;
    const int wr = w >> 1, wc = w & 1;
    const int nbx = gridDim.x;
    const int wg = xcd_swz(blockIdx.y*nbx + blockIdx.x, nbx*gridDim.y);
    const int row0 = (wg / nbx) * 128, col0 = (wg % nbx) * 128;

    const int srow = w*32 + (lane >> 2);
    const int sch  = lane & 3;
    const int scolA = (sch ^ (srow & 3)) * 8;
    const ushort* gA0 = A  + (size_t)(row0 + srow)      * lda + scolA;
    const ushort* gA1 = A  + (size_t)(row0 + srow + 16) * lda + scolA;
    const ushort* gB0 = Wt + (size_t)(col0 + srow)      * K   + scolA;
    const ushort* gB1 = Wt + (size_t)(col0 + srow + 16) * K   + scolA;
    const int d0 = srow*32 + sch*8, d1 = (srow+16)*32 + sch*8;

    f4 zero4 = {0.f,0.f,0.f,0.f};
    f4 acc[4][4];
    #pragma unroll
    for (int i=0;i<4;i++)
        #pragma unroll
        for (int j=0;j<4;j++) acc[i][j] = zero4;

    const int fr = lane & 15;
    const int pcr = (((lane >> 4) ^ (fr & 3))) * 8;
    gload16(gA0, &lA[0][d0]); gload16(gA1, &lA[0][d1]);
    gload16(gB0, &lB[0][d0]); gload16(gB1, &lB[0][d1]);
    __syncthreads();
    int cur = 0;
    for (int kt = 0; kt < K; kt += 32) {
        int nxt = cur ^ 1;
        if (kt + 32 < K) {
            gload16(gA0 + kt + 32, &lA[nxt][d0]); gload16(gA1 + kt + 32, &lA[nxt][d1]);
            gload16(gB0 + kt + 32, &lB[nxt][d0]); gload16(gB1 + kt + 32, &lB[nxt][d1]);
        }
        bh8 af[4], bfr[4];
        #pragma unroll
        for (int i=0;i<4;i++){
            af[i]  = *(const bh8*)&lA[cur][(wr*64 + i*16 + fr)*32 + pcr];
            bfr[i] = *(const bh8*)&lB[cur][(wc*64 + i*16 + fr)*32 + pcr];
        }
        #pragma unroll
        for (int i=0;i<4;i++)
            #pragma unroll
            for (int j=0;j<4;j++)
                acc[i][j] = __builtin_amdgcn_mfma_f32_16x16x32_bf16(af[i], bfr[j], acc[i][j], 0, 0, 0);
        __syncthreads();
        cur = nxt;
    }

    const int seg = col0 >> 9;
    if (seg == 5) {
        #pragma unroll
        for (int i=0;i<4;i++){
            int rr = row0 + wr*64 + i*16 + ((lane >> 4) << 2);
            #pragma unroll
            for (int j=0;j<4;j++){
                int lcc = (col0 - 2560) + wc*64 + j*16 + (lane & 15);
                float bv = bs5[lcc];
                #pragma unroll
                for (int q=0;q<4;q++){
                    int r = rr + q;
                    float ph = tanhf_fast(acc[i][j][q] + bv)*PI_F;
                    Qc[(size_t)r*128 + lcc] = f2b(__cosf(ph));
                    Qs[(size_t)r*128 + lcc] = f2b(__sinf(ph));
                }
            }
        }
        return;
    }
    const float* bias = seg==0?bs0: seg==1?bs1: seg==2?bs2: seg==3?bs3: bs4;
    ushort* dst = seg==0?o0: seg==1?o1p: seg==2?o2p: seg==3?o3p: o4p;
    float msc = fabsf(*magscp);
    #pragma unroll
    for (int i=0;i<4;i++){
        int rr = row0 + wr*64 + i*16 + ((lane >> 4) << 2);
        #pragma unroll
        for (int j=0;j<4;j++){
            int cc = col0 + wc*64 + j*16 + (lane & 15);
            int lcc = cc & 511;
            float bv = bias[lcc];
            float csc = (seg==0) ? fabsf(omsc[lcc]) : 1.0f;
            #pragma unroll
            for (int q=0;q<4;q++){
                int r = rr + q;
                float t = acc[i][j][q] + bv;
                if (seg==1)      t = msc/(1.0f+__expf(-t));
                else if (seg==3) t = geluf(t);
                else             t *= csc;
                dst[(size_t)r*512 + lcc] = f2b(t);
            }
        }
    }
}

// dual-A GEMM: BK=32 2-phase + 4-chunk swizzle. M=640, K=512.
__global__ __launch_bounds__(256, 2)
void mgemm_k(const ushort* __restrict__ Apos, const ushort* __restrict__ Ask,
             const ushort* __restrict__ Wm1o, const ushort* __restrict__ Wsk2,
             const float* __restrict__ bm1o, const float* __restrict__ bsk2,
             ushort* __restrict__ planes, ushort* __restrict__ Kc, ushort* __restrict__ Ks)
{
    __shared__ ushort lA[2][128*32];
    __shared__ ushort lB[2][128*32];
    const int tid = threadIdx.x, lane = tid & 63, w = tid >> 6;
    const int wr = w >> 1, wc = w & 1;
    const int nbx = gridDim.x;
    const int wg = xcd_swz(blockIdx.y*nbx + blockIdx.x, nbx*gridDim.y);
    const int row0 = (wg / nbx) * 128, col0 = (wg % nbx) * 128;
    const int seg = col0 >> 9;
    const ushort* A  = seg ? Ask  : Apos;
    const ushort* Wt = seg ? Wsk2 : Wm1o;
    const int wcol0 = seg ? (col0 - 512) : col0;
    const int K = 512;

    const int srow = w*32 + (lane >> 2);
    const int sch  = lane & 3;
    const int scolA = (sch ^ (srow & 3)) * 8;
    const ushort* gA0 = A  + (size_t)(row0 + srow)       * 512 + scolA;
    const ushort* gA1 = A  + (size_t)(row0 + srow + 16)  * 512 + scolA;
    const ushort* gB0 = Wt + (size_t)(wcol0 + srow)      * 512 + scolA;
    const ushort* gB1 = Wt + (size_t)(wcol0 + srow + 16) * 512 + scolA;
    const int d0 = srow*32 + sch*8, d1 = (srow+16)*32 + sch*8;

    f4 zero4 = {0.f,0.f,0.f,0.f};
    f4 acc[4][4];
    #pragma unroll
    for (int i=0;i<4;i++)
        #pragma unroll
        for (int j=0;j<4;j++) acc[i][j] = zero4;

    const int fr = lane & 15;
    const int pcr = (((lane >> 4) ^ (fr & 3))) * 8;
    gload16(gA0, &lA[0][d0]); gload16(gA1, &lA[0][d1]);
    gload16(gB0, &lB[0][d0]); gload16(gB1, &lB[0][d1]);
    __syncthreads();
    int cur = 0;
    for (int kt = 0; kt < K; kt += 32) {
        int nxt = cur ^ 1;
        if (kt + 32 < K) {
            gload16(gA0 + kt + 32, &lA[nxt][d0]); gload16(gA1 + kt + 32, &lA[nxt][d1]);
            gload16(gB0 + kt + 32, &lB[nxt][d0]); gload16(gB1 + kt + 32, &lB[nxt][d1]);
        }
        bh8 af[4], bfr[4];
        #pragma unroll
        for (int i=0;i<4;i++){
            af[i]  = *(const bh8*)&lA[cur][(wr*64 + i*16 + fr)*32 + pcr];
            bfr[i] = *(const bh8*)&lB[cur][(wc*64 + i*16 + fr)*32 + pcr];
        }
        #pragma unroll
        for (int i=0;i<4;i++)
            #pragma unroll
            for (int j=0;j<4;j++)
                acc[i][j] = __builtin_amdgcn_mfma_f32_16x16x32_bf16(af[i], bfr[j], acc[i][j], 0, 0, 0);
        __syncthreads();
        cur = nxt;
    }

    #pragma unroll
    for (int i=0;i<4;i++){
        int rr = row0 + wr*64 + i*16 + ((lane >> 4) << 2);
        #pragma unroll
        for (int j=0;j<4;j++){
            int cc = col0 + wc*64 + j*16 + (lane & 15);
            #pragma unroll
            for (int q=0;q<4;q++){
                int r = rr + q;
                if (seg == 0){
                    planes[(size_t)r*2048 + cc] = f2b(acc[i][j][q] + bm1o[cc]);
                } else {
                    int lcc = cc - 512;
                    float ph = tanhf_fast(acc[i][j][q] + bsk2[lcc])*PI_F;
                    Kc[(size_t)r*128 + lcc] = f2b(__cosf(ph));
                    Ks[(size_t)r*128 + lcc] = f2b(__sinf(ph));
                }
            }
        }
    }
}

// all weight transposes in ONE dispatch
struct WtArgs {
    const float* src[12];
    ushort* dst[12];
    int K[12], M[12], t0[13];
};
__global__ __launch_bounds__(256)
void wtall_k(WtArgs a)
{
    __shared__ float tile[32][33];
    int bb = blockIdx.x;
    int j = 0;
    while (bb >= a.t0[j+1]) ++j;
    int tt = bb - a.t0[j];
    int K = a.K[j], M = a.M[j];
    int mt = M >> 5;
    int kb = (tt / mt) * 32, mb = (tt % mt) * 32;
    const float* W = a.src[j]; ushort* Wt = a.dst[j];
    int tx = threadIdx.x & 31, ty = threadIdx.x >> 5;
    #pragma unroll
    for (int i = ty; i < 32; i += 8)
        tile[i][tx] = W[(size_t)(kb+i)*M + mb+tx];
    __syncthreads();
    #pragma unroll
    for (int i = ty; i < 32; i += 8)
        Wt[(size_t)(mb+i)*K + kb+tx] = f2b(tile[tx][i]);
}

// fconv: fp32 x -> bf16 xctx cols 0..511 AND chunk sums csX
__global__ __launch_bounds__(256)
void fconv_k(const float* __restrict__ in, ushort* __restrict__ xctx,
             float* __restrict__ csX)
{
    int bc = blockIdx.x;
    int t = threadIdx.x;
    int d = t*2;
    size_t row0 = (size_t)bc * CL;
    float s0=0.f, s1=0.f;
    for (int l=0;l<CL;l++){
        float2 v = *(const float2*)(in + (row0+l)*D_ + d);
        ushort h0 = f2b(v.x), h1 = f2b(v.y);
        xctx[(row0+l)*1024 + d]   = h0;
        xctx[(row0+l)*1024 + d+1] = h1;
        s0 += b2f(h0); s1 += b2f(h1);
    }
    csX[(size_t)bc*512 + d]   = s0;
    csX[(size_t)bc*512 + d+1] = s1;
}

// ---------------- s1 scans ----------------
__global__ __launch_bounds__(256)
void s1a_k(const ushort* __restrict__ omega, float* __restrict__ csA)
{
    int bid = blockIdx.x;
    int bc = bid >> 1, dg = bid & 1;
    int d = dg*256 + threadIdx.x;
    size_t base = ((size_t)bc*CL)*D_ + d;
    float sA=0.f;
    for (int l=0;l<CL;l++) sA += b2f(omega[base + (size_t)l*D_]);
    csA[(size_t)bc*D_ + d] = sA;
}

__global__ __launch_bounds__(256)
void aux1_k(float* __restrict__ csA, float* __restrict__ csX,
            const float* __restrict__ sgate, float* __restrict__ rinv, int nb2)
{
    __shared__ float wsum[4];
    __shared__ float carry;
    int bb = blockIdx.x, t = threadIdx.x;
    if (bb < 2*nb2){
        float* buf = (bb < nb2) ? csA : csX;
        int gb = (bb < nb2) ? bb : bb - nb2;
        int tt = gb*256 + t;
        int b = tt >> 9, d = tt & 511;
        float* p = buf + ((size_t)b*NC)*D_ + d;
        float run=0.f;
        for (int c=0;c<NC;c++){
            float v = p[(size_t)c*D_];
            p[(size_t)c*D_] = run;
            run += v;
        }
        return;
    }
    int b = bb - 2*nb2;
    int lane = t & 63, wave = t >> 6;
    if (t == 0) carry = 0.f;
    __syncthreads();
    for (int s = 0; s < L_/256; s++){
        float v = sgate[(size_t)b*L_ + s*256 + t];
        float sc = v;
        #pragma unroll
        for (int off=1; off<64; off<<=1){
            float u = __shfl_up(sc, off, 64);
            if (lane >= off) sc += u;
        }
        if (lane == 63) wsum[wave] = sc;
        __syncthreads();
        float woff = carry;
        for (int w2 = 0; w2 < wave; w2++) woff += wsum[w2];
        float inc = sc + woff;
        rinv[(size_t)b*L_ + s*256 + t] = rsqrtf(fmaxf(inc, 1.0f));
        __syncthreads();
        if (t == 255) carry = inc;
        __syncthreads();
    }
}

__global__ void prefix_k(float* a, float* b2v, float* c3, int nb2)
{
    int bb = blockIdx.x;
    float* bufs[3] = {a,b2v,c3};
    float* buf = bufs[bb / nb2];
    int gb = bb % nb2;
    int tt = gb*256 + threadIdx.x;
    int b = tt >> 9, d = tt & 511;
    float* p = buf + ((size_t)b*NC)*D_ + d;
    float run=0.f;
    for (int c=0;c<NC;c++){
        float v = p[(size_t)c*D_];
        p[(size_t)c*D_] = run;
        run += v;
    }
}

__global__ __launch_bounds__(256)
void s1c_k(const ushort* __restrict__ omega, const ushort* __restrict__ phi_init,
           const ushort* __restrict__ magn, const ushort* __restrict__ v1,
           const float* __restrict__ csA, const float* __restrict__ csX,
           ushort* __restrict__ cphi, ushort* __restrict__ sphi, ushort* __restrict__ xctx,
           float* __restrict__ csM, float* __restrict__ csC, float* __restrict__ csS)
{
    int bid = blockIdx.x;
    int b = bid >> 7; int rem = bid & 127;
    int dg = rem & 1, c = rem >> 1;
    int d = dg*256 + threadIdx.x;
    size_t ci = ((size_t)b*NC + c)*D_ + d;
    float phiacc = csA[ci], xacc = csX[ci];
    float sM=0.f,sC=0.f,sS=0.f;
    size_t xrow = (size_t)b*L_ + (size_t)c*CL;
    size_t base = xrow*D_ + d;
    for (int l=0;l<CL;l++){
        size_t idx = base + (size_t)l*D_;
        phiacc += b2f(omega[idx]);
        float ph = b2f(phi_init[idx]) + phiacc;
        float spv = __sinf(ph), cpv = __cosf(ph);
        cphi[idx] = f2b(cpv); sphi[idx] = f2b(spv);
        xacc += b2f(xctx[(xrow + l)*1024 + d]);
        xctx[(xrow + l)*1024 + 512 + d] = f2b(__fdividef(xacc, (float)(c*CL + l + 1)));
        float m = b2f(magn[idx]); sM += m;
        float wv = m * b2f(v1[idx]);
        sC = fmaf(wv, cpv, sC); sS = fmaf(wv, spv, sS);
    }
    csM[ci]=sM; csC[ci]=sC; csS[ci]=sS;
}

__global__ __launch_bounds__(256)
void s1e_k(const ushort* __restrict__ magn, const ushort* __restrict__ v1,
           const ushort* qoff, const ushort* __restrict__ cphi, const ushort* __restrict__ sphi,
           const float* __restrict__ csM, const float* __restrict__ csC,
           const float* __restrict__ csS, ushort* pos_ret)
{
    int bid = blockIdx.x;
    int b = bid >> 7; int rem = bid & 127;
    int dg = rem & 1, c = rem >> 1;
    int d = dg*256 + threadIdx.x;
    size_t ci = ((size_t)b*NC + c)*D_ + d;
    float mA=csM[ci], cA=csC[ci], sA=csS[ci];
    size_t base = ((size_t)b*L_ + (size_t)c*CL)*D_ + d;
    for (int l=0;l<CL;l++){
        size_t idx = base + (size_t)l*D_;
        float m = b2f(magn[idx]); mA += m;
        float wv = m * b2f(v1[idx]);
        float cp = b2f(cphi[idx]), sp = b2f(sphi[idx]);
        cA = fmaf(wv, cp, cA); sA = fmaf(wv, sp, sA);
        float rs = rsqrtf(mA + 1e-8f);
        float qo = b2f(qoff[idx]);
        float sq = __sinf(qo), cq = __cosf(qo);
        float cosq = cp*cq - sp*sq;
        float sinq = sp*cq + cp*sq;
        pos_ret[idx] = f2b((cA*cosq + sA*sinq) * rs * 0.04419417382415922f);
    }
}

__global__ __launch_bounds__(256)
void vencsg_k(const ushort* __restrict__ xctx, const float* __restrict__ Wv,
              const float* __restrict__ bv, const float* __restrict__ Wg,
              const float* __restrict__ bg,
              ushort* __restrict__ gvb, float* __restrict__ sgate)
{
    int gw = (int)((blockIdx.x*(size_t)blockDim.x + threadIdx.x) >> 6);
    int lane = threadIdx.x & 63;
    const ushort* xr = xctx + (size_t)gw*1024;
    float pv[8] = {0,0,0,0,0,0,0,0}; float pg = 0.f;
    #pragma unroll
    for (int j=0;j<8;j++){
        int k = lane + 64*j;
        float xv = b2f(xr[k]);
        #pragma unroll
        for (int v=0;v<8;v++) pv[v] = fmaf(xv, Wv[k*8+v], pv[v]);
        pg = fmaf(xv, Wg[k], pg);
    }
    #pragma unroll
    for (int off=32; off>0; off>>=1){
        #pragma unroll
        for (int v=0;v<8;v++) pv[v] += __shfl_down(pv[v], off, 64);
        pg += __shfl_down(pg, off, 64);
    }
    if (lane==0){
        float sg = 1.0f/(1.0f+__expf(-(pg + bg[0])));
        #pragma unroll
        for (int v=0;v<8;v++) gvb[(size_t)gw*8+v] = f2b((pv[v] + bv[v]) * sg);
        sgate[gw] = sg;
    }
}

__global__ __launch_bounds__(256)
void kvsum_k(const ushort* __restrict__ Kc, const ushort* __restrict__ Ks,
             const ushort* __restrict__ gvb, float* __restrict__ csKV)
{
    int bid = blockIdx.x;
    int b = bid >> 6, c = bid & 63;
    int t = threadIdx.x; int p = t & 127; int v0 = (t>>7)*4;
    size_t row0 = (size_t)b*L_ + (size_t)c*64;
    float ac[4]={0,0,0,0}, as[4]={0,0,0,0};
    for (int l=0;l<64;l++){
        size_t r = row0 + l;
        float kc = b2f(Kc[r*(size_t)P_ + p]);
        float ks = b2f(Ks[r*(size_t)P_ + p]);
        #pragma unroll
        for (int j=0;j<4;j++){
            float gv = b2f(gvb[r*(size_t)V_ + v0 + j]);
            ac[j] = fmaf(kc, gv, ac[j]);
            as[j] = fmaf(ks, gv, as[j]);
        }
    }
    float* base = csKV + ((size_t)b*64 + c)*2048;
    #pragma unroll
    for (int j=0;j<4;j++){
        base[p*V_ + v0 + j] = ac[j];
        base[1024 + p*V_ + v0 + j] = as[j];
    }
}

__global__ void kvpfx_k(float* __restrict__ csKV)
{
    int t = blockIdx.x*blockDim.x + threadIdx.x;
    int b = t >> 11, si = t & 2047;
    float* ptr = csKV + ((size_t)b*64)*2048 + si;
    float run=0.f;
    for (int c=0;c<64;c++){
        float v = ptr[(size_t)c*2048];
        ptr[(size_t)c*2048] = run;
        run += v;
    }
}

__global__ __launch_bounds__(256)
void kv2_k(const ushort* __restrict__ Qc, const ushort* __restrict__ Qs,
           const ushort* __restrict__ Kc, const ushort* __restrict__ Ks,
           const ushort* __restrict__ gvb, const float* __restrict__ rinv,
           const float* __restrict__ csKV, float* __restrict__ kvret)
{
    __shared__ ushort sS[64][66];
    __shared__ float sM[2048];
    __shared__ float sgv[64][8];
    int tile = blockIdx.x, b = blockIdx.y;
    int t = threadIdx.x, lane = t & 63, w = t >> 6;
    int wr = w >> 1, wc = w & 1;
    size_t row0 = (size_t)b*L_ + (size_t)tile*64;
    const float* kvb = csKV + ((size_t)b*64 + tile)*2048;
    #pragma unroll
    for (int k=0;k<8;k++) sM[t + k*256] = kvb[t + k*256];
    #pragma unroll
    for (int k=0;k<2;k++){
        int idx = t + k*256; int l = idx >> 3, v = idx & 7;
        sgv[l][v] = b2f(gvb[(row0 + l)*(size_t)V_ + v]);
    }
    f4 zero4 = {0.f,0.f,0.f,0.f};
    f4 acc[2][2];
    #pragma unroll
    for (int i=0;i<2;i++)
        #pragma unroll
        for (int j=0;j<2;j++) acc[i][j] = zero4;
    #pragma unroll
    for (int ks=0; ks<8; ks++){
        const ushort* Ab = (ks<4) ? Qc : Qs;
        const ushort* Bb = (ks<4) ? Kc : Ks;
        int kb = (ks&3)*32 + (lane>>4)*8;
        bh8 af[2], bfr[2];
        #pragma unroll
        for (int i=0;i<2;i++)
            af[i] = *(const bh8*)(Ab + (row0 + wr*32 + i*16 + (lane&15))*(size_t)P_ + kb);
        #pragma unroll
        for (int j=0;j<2;j++)
            bfr[j] = *(const bh8*)(Bb + (row0 + wc*32 + j*16 + (lane&15))*(size_t)P_ + kb);
        #pragma unroll
        for (int i=0;i<2;i++)
            #pragma unroll
            for (int j=0;j<2;j++)
                acc[i][j] = __builtin_amdgcn_mfma_f32_16x16x32_bf16(af[i], bfr[j], acc[i][j], 0, 0, 0);
    }
    #pragma unroll
    for (int i=0;i<2;i++){
        #pragma unroll
        for (int j=0;j<2;j++){
            int cc = wc*32 + j*16 + (lane & 15);
            #pragma unroll
            for (int q=0;q<4;q++){
                int lr = wr*32 + i*16 + ((lane>>4)<<2) + q;
                sS[lr][cc] = f2b((cc <= lr) ? acc[i][j][q] : 0.f);
            }
        }
    }
    __syncthreads();
    int l = t & 63, vh = t >> 6; int v0 = vh*2;
    const ushort* qcr = Qc + (row0 + l)*(size_t)P_;
    const ushort* qsr = Qs + (row0 + l)*(size_t)P_;
    float a0=0.f, a1=0.f;
    #pragma unroll
    for (int pc=0; pc<16; pc++){
        bh8 qc8 = *(const bh8*)(qcr + pc*8);
        bh8 qs8 = *(const bh8*)(qsr + pc*8);
        #pragma unroll
        for (int e=0;e<8;e++){
            int p = pc*8+e;
            float qc = b2f((ushort)qc8[e]), qs = b2f((ushort)qs8[e]);
            a0 += qc*sM[p*8+v0]   + qs*sM[1024+p*8+v0];
            a1 += qc*sM[p*8+v0+1] + qs*sM[1024+p*8+v0+1];
        }
    }
    for (int c=0;c<64;c++){
        float sv = b2f(sS[l][c]);
        a0 = fmaf(sv, sgv[c][v0],   a0);
        a1 = fmaf(sv, sgv[c][v0+1], a1);
    }
    float rn = rinv[row0 + l] * 0.08838834764831845f;
    kvret[(row0+l)*(size_t)V_ + v0]   = a0*rn;
    kvret[(row0+l)*(size_t)V_ + v0+1] = a1*rn;
}

// combined + LN; kv_out in-register from kvret; x from xctx bf16
__global__ __launch_bounds__(256)
void cmb_k(const ushort* __restrict__ xctx, const ushort* __restrict__ cphi,
           const ushort* __restrict__ sphi,
           const float* __restrict__ kvret, const float* __restrict__ Wkvo,
           const float* __restrict__ bkvo,
           const float* __restrict__ ln_g, const float* __restrict__ ln_b,
           ushort* pl)
{
    __shared__ float red[8];
    __shared__ float kvv[8];
    int n = blockIdx.x; int t = threadIdx.x;
    int wave = t>>6, lane = t&63;
    if (t < 8) kvv[t] = kvret[(size_t)n*8 + t];
    __syncthreads();
    float v_[8]; float sum=0.f, sumsq=0.f;
    #pragma unroll
    for (int i=0;i<8;i++){
        int cidx = t + i*256;
        int seg = cidx >> 9, cc = cidx & 511;
        float v;
        if (seg == 0) v = b2f(pl[(size_t)n*2048 + cidx]);
        else if (seg == 1) {
            v = bkvo[cc];
            #pragma unroll
            for (int vv=0; vv<8; vv++) v = fmaf(kvv[vv], Wkvo[vv*512 + cc], v);
        } else {
            size_t id = (size_t)n*D_ + cc;
            v = b2f(xctx[(size_t)n*1024 + cc]) * b2f((seg==2) ? cphi[id] : sphi[id]);
        }
        v_[i]=v; sum += v; sumsq = fmaf(v,v,sumsq);
    }
    #pragma unroll
    for (int off=32; off>0; off>>=1){
        sum += __shfl_xor(sum, off, 64);
        sumsq += __shfl_xor(sumsq, off, 64);
    }
    if (lane==0){ red[wave]=sum; red[wave+4]=sumsq; }
    __syncthreads();
    float s = red[0]+red[1]+red[2]+red[3];
    float q = red[4]+red[5]+red[6]+red[7];
    float mu = s * (1.0f/2048.0f);
    float var = q * (1.0f/2048.0f) - mu*mu;
    float rstd = rsqrtf(var + 1e-5f);
    #pragma unroll
    for (int i=0;i<8;i++){
        int cidx = t + i*256;
        float h = (v_[i]-mu)*rstd*ln_g[cidx] + ln_b[cidx];
        pl[(size_t)n*2048 + cidx] = f2b(h);
    }
}

__global__ void copyx_k(const float* __restrict__ x, float* __restrict__ out, size_t n)
{
    size_t i = (size_t)blockIdx.x*256 + threadIdx.x;
    if (i < n) out[i] = x[i];
}

// ---------------- host ----------------
struct WS {
    ushort *wt_fused,*wt_pi2,*wt_sk1,*wt_sk2,*wt_m1o,*wt_o1,*wt_o2;
    ushort *xctx, *pool;
    ushort *Qc,*Qs,*Kc,*Ks,*gvb,*cphi,*sphi;
    float *sgate,*rinv,*kvret;
    float *csA,*csX,*csM,*csC,*csS,*csKV;
};

static size_t ws_layout(WS& w, char* base, int NB)
{
    size_t off = 0;
    auto al = [&](size_t bytes)->char* {
        char* p = base + off; off = (off + bytes + 255) & ~(size_t)255; return p;
    };
    size_t R = (size_t)NB * L_;
    w.wt_fused=(ushort*)al((size_t)2688*512*2);
    w.wt_pi2 =(ushort*)al(512*512*2);
    w.wt_sk1 =(ushort*)al((size_t)512*1024*2); w.wt_sk2=(ushort*)al(128*512*2);
    w.wt_m1o =(ushort*)al(512*512*2);
    w.wt_o1  =(ushort*)al((size_t)1024*2048*2); w.wt_o2=(ushort*)al((size_t)512*1024*2);
    w.xctx=(ushort*)al(R*1024*2);
    w.pool=(ushort*)al(R*512*2*6);
    w.Qc=(ushort*)al(R*128*2); w.Qs=(ushort*)al(R*128*2);
    w.Kc=(ushort*)al(R*128*2); w.Ks=(ushort*)al(R*128*2);
    w.gvb=(ushort*)al(R*8*2);
    w.cphi=(ushort*)al(R*512*2); w.sphi=(ushort*)al(R*512*2);
    w.sgate=(float*)al(R*4); w.rinv=(float*)al(R*4); w.kvret=(float*)al(R*8*4);
    w.csA=(float*)al((size_t)NB*NC*512*4); w.csX=(float*)al((size_t)NB*NC*512*4);
    w.csM=(float*)al((size_t)NB*NC*512*4); w.csC=(float*)al((size_t)NB*NC*512*4);
    w.csS=(float*)al((size_t)NB*NC*512*4);
    w.csKV=(float*)al((size_t)NB*64*2048*4);
    return off;
}

extern "C" void kernel_launch(void* const* d_in, const int* in_sizes, int n_in,
                              void* d_out, int out_size, void* d_ws, size_t ws_size,
                              hipStream_t stream)
{
    const float* x        =(const float*)d_in[0];
    const float* W_omega  =(const float*)d_in[1];  const float* b_omega=(const float*)d_in[2];
    const float* omega_sc =(const float*)d_in[3];
    const float* W_pi1    =(const float*)d_in[4];  const float* b_pi1 =(const float*)d_in[5];
    const float* W_pi2    =(const float*)d_in[6];  const float* b_pi2 =(const float*)d_in[7];
    const float* W_m1v    =(const float*)d_in[8];  const float* b_m1v =(const float*)d_in[9];
    const float* W_m1o    =(const float*)d_in[10]; const float* b_m1o =(const float*)d_in[11];
    const float* W_mag    =(const float*)d_in[12]; const float* b_mag =(const float*)d_in[13];
    const float* mag_sc   =(const float*)d_in[14];
    const float* W_qoff   =(const float*)d_in[15]; const float* b_qoff=(const float*)d_in[16];
    const float* W_kenc   =(const float*)d_in[17]; const float* b_kenc=(const float*)d_in[18];
    const float* W_venc   =(const float*)d_in[19]; const float* b_venc=(const float*)d_in[20];
    const float* W_sk1    =(const float*)d_in[21]; const float* b_sk1 =(const float*)d_in[22];
    const float* W_sk2    =(const float*)d_in[23]; const float* b_sk2 =(const float*)d_in[24];
    const float* W_sg     =(const float*)d_in[25]; const float* b_sg  =(const float*)d_in[26];
    const float* W_kvo    =(const float*)d_in[27]; const float* b_kvo =(const float*)d_in[28];
    const float* ln_g     =(const float*)d_in[29]; const float* ln_b  =(const float*)d_in[30];
    const float* W_o1     =(const float*)d_in[31]; const float* b_o1  =(const float*)d_in[32];
    const float* W_o2     =(const float*)d_in[33]; const float* b_o2  =(const float*)d_in[34];
    float* out = (float*)d_out;

    char* wsb = (char*)d_ws;
    WS w;
    int NB = 4;
    if (ws_layout(w, wsb, 4) > ws_size) {
        NB = 2;
        if (ws_layout(w, wsb, 2) > ws_size) {
            NB = 1;
            if (ws_layout(w, wsb, 1) > ws_size) {
                copyx_k<<<dim3((unsigned)(((size_t)N_*D_ + 255)/256)), dim3(256), 0, stream>>>(x, out, (size_t)N_*D_);
                return;
            }
        }
    }

    dim3 blk(256);
    WtArgs wa;
    const float* srcs[12] = {W_omega, W_mag, W_m1v, W_pi1, W_qoff, W_kenc,
                             W_pi2, W_sk1, W_sk2, W_m1o, W_o1, W_o2};
    ushort* dsts[12] = {w.wt_fused + (size_t)0*512*512, w.wt_fused + (size_t)1*512*512,
                        w.wt_fused + (size_t)2*512*512, w.wt_fused + (size_t)3*512*512,
                        w.wt_fused + (size_t)4*512*512, w.wt_fused + (size_t)5*512*512,
                        w.wt_pi2, w.wt_sk1, w.wt_sk2, w.wt_m1o, w.wt_o1, w.wt_o2};
    int Ks_[12] = {512,512,512,512,512,512, 512,1024,512,512,2048,1024};
    int Ms_[12] = {512,512,512,512,512,128, 512, 512,128,512,1024, 512};
    int cum = 0;
    for (int j = 0; j < 12; ++j){
        wa.src[j]=srcs[j]; wa.dst[j]=dsts[j]; wa.K[j]=Ks_[j]; wa.M[j]=Ms_[j];
        wa.t0[j]=cum; cum += (Ks_[j]/32)*(Ms_[j]/32);
    }
    wa.t0[12]=cum;
    wtall_k<<<dim3(cum), blk, 0, stream>>>(wa);

    const int R = NB * L_;
    const size_t SL = (size_t)R * 512;
    ushort* bA = w.pool;        ushort* bB = w.pool + SL;
    ushort* bC = w.pool + 2*SL; ushort* bD = w.pool + 3*SL;
    ushort* bE = w.pool + 4*SL; ushort* bF = w.pool + 5*SL;
    ushort* planes = w.pool;               // [R][2048] = slots 0-3
    ushort* h1 = w.pool + 4*SL;            // [R][1024] = slots 4-5

    #define DGEMM(ACT,A,lda,Wt_,bias_,Ob_,Of_,ldc,K_,M_,add_) \
        dgemm_k<ACT><<<dim3((M_)/128, R/128), blk, 0, stream>>>(A,lda,Wt_,bias_,Ob_,Of_,ldc,K_,add_)
    #define EGEMM(ACT,A,lda,Wt_,bias_,Ob_,Of_,ldc,K_,M_,add_) \
        egemm_k<ACT><<<dim3((M_)/256, R/256), dim3(512), 0, stream>>>(A,lda,Wt_,bias_,Ob_,Of_,ldc,K_,add_)

    for (int g = 0; g < B_/NB; ++g) {
        const float* xg = x + (size_t)g*NB*LD;
        float* outg = out + (size_t)g*NB*LD;

        fconv_k<<<dim3(NB*NC), blk, 0, stream>>>(xg, w.xctx, w.csX);

        fgemm_k<<<dim3(2688/128, R/128), blk, 0, stream>>>(
            w.xctx,1024, w.wt_fused, b_omega,b_mag,b_m1v,b_pi1,b_qoff,b_kenc,
            bA,bB,bC,bD,bF, w.Qc,w.Qs, omega_sc, mag_sc, 512);
        DGEMM(0, bD,512, w.wt_pi2, b_pi2, bE,(float*)0, 512, 512,512, (const float*)0);  // phi_init -> bE
        vencsg_k<<<dim3((unsigned)((size_t)R*64/256)), blk, 0, stream>>>(w.xctx, W_venc,b_venc, W_sg,b_sg, w.gvb, w.sgate);
        s1a_k<<<dim3(NB*NC*2), blk, 0, stream>>>(bA, w.csA);
        aux1_k<<<dim3(NB*4 + NB), blk, 0, stream>>>(w.csA, w.csX, w.sgate, w.rinv, NB*2);
        s1c_k<<<dim3(NB*NC*2), blk, 0, stream>>>(bA, bE, bB, bC, w.csA, w.csX,
                                                 w.cphi, w.sphi, w.xctx, w.csM, w.csC, w.csS);
        prefix_k<<<dim3(NB*6), blk, 0, stream>>>(w.csM, w.csC, w.csS, NB*2);
        s1e_k<<<dim3(NB*NC*2), blk, 0, stream>>>(bB, bC, bF, w.cphi, w.sphi,
                                                 w.csM, w.csC, w.csS, bF);              // bF = pos_ret

        DGEMM(1, w.xctx,1024, w.wt_sk1, b_sk1, bE,(float*)0, 512, 1024,512, (const float*)0); // sk1g -> bE
        mgemm_k<<<dim3(640/128, R/128), blk, 0, stream>>>(
            bF, bE, w.wt_m1o, w.wt_sk2, b_m1o, b_sk2, planes, w.Kc, w.Ks);

        kvsum_k<<<dim3(NB*64), blk, 0, stream>>>(w.Kc, w.Ks, w.gvb, w.csKV);
        kvpfx_k<<<dim3(NB*8), blk, 0, stream>>>(w.csKV);
        kv2_k<<<dim3(64, NB), blk, 0, stream>>>(w.Qc, w.Qs, w.Kc, w.Ks, w.gvb, w.rinv, w.csKV, w.kvret);

        cmb_k<<<dim3(R), blk, 0, stream>>>(w.xctx, w.cphi, w.sphi, w.kvret, W_kvo, b_kvo,
                                           ln_g, ln_b, planes);
        EGEMM(1, planes,2048, w.wt_o1, b_o1, h1,(float*)0, 1024, 2048,1024, (const float*)0); // h1 (4-phase)
        DGEMM(2, h1,1024, w.wt_o2, b_o2, (ushort*)0,outg, 512, 1024,512, xg);                 // out
    }
    #undef DGEMM
    #undef EGEMM
}